// Round 15
// baseline (715.064 us; speedup 1.0000x reference)
//
#include <hip/hip_runtime.h>

#define LRELU(v) ((v) > 0.f ? (v) : 0.2f * (v))

typedef float f32x4 __attribute__((ext_vector_type(4)));
typedef __bf16 bf16x8 __attribute__((ext_vector_type(8)));
typedef unsigned short ushort8v __attribute__((ext_vector_type(8)));
typedef unsigned int u32x2 __attribute__((ext_vector_type(2)));

__device__ __forceinline__ unsigned short f2bf(float f) {
    unsigned int u = __float_as_uint(f);
    u += 0x7fffu + ((u >> 16) & 1u);
    return (unsigned short)(u >> 16);
}
__device__ __forceinline__ float bf2f(unsigned short h) {
    return __uint_as_float(((unsigned int)h) << 16);
}
__device__ __forceinline__ float sigmoid_fast(float x) {
    float e = __builtin_amdgcn_exp2f(-x * 1.442695041f);
    return __builtin_amdgcn_rcpf(1.f + e);
}
__device__ __forceinline__ float tanh_fast(float x) {
    float e = __builtin_amdgcn_exp2f(x * 2.885390082f);  // e^(2x)
    return 1.f - 2.f * __builtin_amdgcn_rcpf(e + 1.f);
}
__device__ __forceinline__ float exp_fast(float x) {
    return __builtin_amdgcn_exp2f(x * 1.442695041f);
}
// quad_perm DPP adds (VALU pipe)
__device__ __forceinline__ float dpp_add_xor1(float v) {
    int r = __builtin_amdgcn_mov_dpp(__float_as_int(v), 0xB1, 0xF, 0xF, true);
    return v + __int_as_float(r);
}
__device__ __forceinline__ float dpp_add_xor2(float v) {
    int r = __builtin_amdgcn_mov_dpp(__float_as_int(v), 0x4E, 0xF, 0xF, true);
    return v + __int_as_float(r);
}

// ---------------------------------------------------------------------------
// ONE prepack kernel: all weight transforms + mask decode, segmented by block.
// ---------------------------------------------------------------------------
__device__ __forceinline__ void wtpack(const float* __restrict__ W,
                                       unsigned short* __restrict__ h,
                                       unsigned short* __restrict__ l, int K,
                                       int N, long idx) {
    int n = (int)(idx / K), k = (int)(idx % K);
    float v = W[(long)k * N + n];
    unsigned short hi = f2bf(v);
    h[idx] = hi;
    l[idx] = f2bf(v - bf2f(hi));
}
// lane-coalesced quad layout (round-10): up[(g*8+q)*2048 + t*4 + i]
__device__ __forceinline__ void ugpack(const float* __restrict__ U,
                                       float* __restrict__ up, int widx) {
    int quad = widx >> 11;
    int rem = widx & 2047;
    int t = rem >> 2, i = rem & 3;
    int g = quad >> 3, q = quad & 7;
    int c = t >> 2, kq = t & 3;
    up[widx] = U[(long)(kq * 32 + q * 4 + i) * 384 + g * 128 + c];
}

__global__ __launch_bounds__(256) void prepack_all(
    const float* __restrict__ w2, unsigned short* __restrict__ bth,
    unsigned short* __restrict__ btl, const float* __restrict__ g1fW,
    unsigned short* __restrict__ wt1fh, unsigned short* __restrict__ wt1fl,
    const float* __restrict__ g1bW, unsigned short* __restrict__ wt1bh,
    unsigned short* __restrict__ wt1bl, const float* __restrict__ g2fW,
    unsigned short* __restrict__ wt2fh, unsigned short* __restrict__ wt2fl,
    const float* __restrict__ g2bW, unsigned short* __restrict__ wt2bh,
    unsigned short* __restrict__ wt2bl, const float* __restrict__ g1fU,
    float* __restrict__ up1f, const float* __restrict__ g1bU,
    float* __restrict__ up1b, const float* __restrict__ g2fU,
    float* __restrict__ up2f, const float* __restrict__ g2bU,
    float* __restrict__ up2b, const float* __restrict__ d1w,
    unsigned short* __restrict__ d1th, unsigned short* __restrict__ d1tl,
    const float* __restrict__ d2w, unsigned short* __restrict__ d2th,
    unsigned short* __restrict__ d2tl, const unsigned int* __restrict__ mraw,
    int* __restrict__ mi) {
    const int bid = blockIdx.x, tid = threadIdx.x;
    if (bid < 512) {
        int idx = bid * 256 + tid;
        int c = idx >> 10, k = idx & 1023;
        float v = w2[k * 128 + c];
        unsigned short hi = f2bf(v);
        bth[(long)c * 1024 + k] = hi;
        btl[(long)c * 1024 + k] = f2bf(v - bf2f(hi));
    } else if (bid < 3008) {
        wtpack(g1fW, wt1fh, wt1fl, 1664, 384, (long)(bid - 512) * 256 + tid);
    } else if (bid < 5504) {
        wtpack(g1bW, wt1bh, wt1bl, 1664, 384, (long)(bid - 3008) * 256 + tid);
    } else if (bid < 5888) {
        wtpack(g2fW, wt2fh, wt2fl, 256, 384, (long)(bid - 5504) * 256 + tid);
    } else if (bid < 6272) {
        wtpack(g2bW, wt2bh, wt2bl, 256, 384, (long)(bid - 5888) * 256 + tid);
    } else if (bid < 6464) {
        ugpack(g1fU, up1f, (bid - 6272) * 256 + tid);
    } else if (bid < 6656) {
        ugpack(g1bU, up1b, (bid - 6464) * 256 + tid);
    } else if (bid < 6848) {
        ugpack(g2fU, up2f, (bid - 6656) * 256 + tid);
    } else if (bid < 7040) {
        ugpack(g2bU, up2b, (bid - 6848) * 256 + tid);
    } else if (bid < 7296) {
        wtpack(d1w, d1th, d1tl, 256, 256, (long)(bid - 7040) * 256 + tid);
    } else if (bid < 7552) {
        wtpack(d2w, d2th, d2tl, 256, 256, (long)(bid - 7296) * 256 + tid);
    } else {
        __shared__ int flag;
        if (tid == 0) flag = 0;
        __syncthreads();
        unsigned a = mraw[tid * 2], bb = mraw[tid * 2 + 1];
        if (a > 1u || bb > 1u) flag = 1;
        __syncthreads();
        if (flag) {
            const unsigned char* b8 = (const unsigned char*)mraw;
            for (int i = tid; i < 2048; i += 256) mi[i] = b8[i] ? 1 : 0;
        } else {
            for (int i = tid; i < 2048; i += 256) mi[i] = mraw[i] ? 1 : 0;
        }
    }
}

// ---------------------------------------------------------------------------
// Fused conv1(fp32)+pool1 -> LDS bf16 hi/lo -> conv2 via split-bf16 MFMA +
// fused leaky+pool2. One block (256 thr, 4 waves) per sequence.
// ---------------------------------------------------------------------------
__global__ __launch_bounds__(256) void conv_kernel(
    const float* __restrict__ x, const float* __restrict__ w1,
    const float* __restrict__ b1, const unsigned short* __restrict__ bth,
    const unsigned short* __restrict__ btl, const float* __restrict__ b2,
    unsigned short* __restrict__ feat_h, unsigned short* __restrict__ feat_l) {
    __shared__ float xs[3][256];
    __shared__ __align__(16) unsigned short p1h[72 * 128];
    __shared__ __align__(16) unsigned short p1l[72 * 128];
    long s = blockIdx.x;
    int tid = threadIdx.x;
    const float* xp = x + s * 768;
    for (int i = tid; i < 768; i += 256) xs[i % 3][i / 3] = xp[i];
    for (int i = tid; i < 10 * 128; i += 256) {
        p1h[62 * 128 + i] = 0;
        p1l[62 * 128 + i] = 0;
    }
    __syncthreads();

    {   // conv1 + pool1, fp32, swizzled bf16 hi/lo store
        int ch = tid & 127;
        int half = tid >> 7;
        float w1r[24];
#pragma unroll
        for (int fc = 0; fc < 24; fc++) w1r[fc] = w1[fc * 128 + ch];
        float bias1 = b1[ch];
        for (int po = half; po < 62; po += 2) {
            int p0 = po * 4;
            float a0 = bias1, a1 = bias1, a2 = bias1, a3 = bias1;
#pragma unroll
            for (int c = 0; c < 3; c++) {
                float xv[11];
#pragma unroll
                for (int q = 0; q < 11; q++) xv[q] = xs[c][p0 + q];
#pragma unroll
                for (int f = 0; f < 8; f++) {
                    float w = w1r[f * 3 + c];
                    a0 = fmaf(xv[f + 0], w, a0);
                    a1 = fmaf(xv[f + 1], w, a1);
                    a2 = fmaf(xv[f + 2], w, a2);
                    a3 = fmaf(xv[f + 3], w, a3);
                }
            }
            float m01 = fmaxf(LRELU(a0), LRELU(a1));
            float m23 = fmaxf(LRELU(a2), LRELU(a3));
            float v = fmaxf(m01, m23);
            unsigned short hi = f2bf(v);
            unsigned short lo = f2bf(v - bf2f(hi));
            int cs = ch ^ ((po & 7) << 3);
            p1h[po * 128 + cs] = hi;
            p1l[po * 128 + cs] = lo;
        }
    }
    __syncthreads();

    const int l = tid & 63, w = tid >> 6;
    const int r = l & 15, g = l >> 4;
    f32x4 acc[4][2];
    const f32x4 zz = {0.f, 0.f, 0.f, 0.f};
#pragma unroll
    for (int m = 0; m < 4; m++) {
        acc[m][0] = zz;
        acc[m][1] = zz;
    }
#pragma unroll 2
    for (int ks = 0; ks < 32; ks++) {
        const int f = ks >> 2;
        const int cin0 = ((ks & 3) << 5) + (g << 3);
        bf16x8 bh[2], bl[2];
#pragma unroll
        for (int n = 0; n < 2; n++) {
            const int c = ((w << 1) + n) * 16 + r;
            const long bo = (long)c * 1024 + (ks << 5) + (g << 3);
            bh[n] = __builtin_bit_cast(bf16x8, *(const ushort8v*)(bth + bo));
            bl[n] = __builtin_bit_cast(bf16x8, *(const ushort8v*)(btl + bo));
        }
        bf16x8 ah[4], al[4];
#pragma unroll
        for (int m = 0; m < 4; m++) {
            const int row = m * 16 + r + f;
            const int col = cin0 ^ ((row & 7) << 3);
            const int off = row * 128 + col;
            ah[m] = __builtin_bit_cast(bf16x8, *(const ushort8v*)(p1h + off));
            al[m] = __builtin_bit_cast(bf16x8, *(const ushort8v*)(p1l + off));
        }
#pragma unroll
        for (int m = 0; m < 4; m++) {
#pragma unroll
            for (int n = 0; n < 2; n++) {
                acc[m][n] = __builtin_amdgcn_mfma_f32_16x16x32_bf16(ah[m], bh[n], acc[m][n], 0, 0, 0);
                acc[m][n] = __builtin_amdgcn_mfma_f32_16x16x32_bf16(ah[m], bl[n], acc[m][n], 0, 0, 0);
                acc[m][n] = __builtin_amdgcn_mfma_f32_16x16x32_bf16(al[m], bh[n], acc[m][n], 0, 0, 0);
            }
        }
    }
#pragma unroll
    for (int m = 0; m < 4; m++) {
        const int j = m * 4 + g;
        if (j < 13) {
#pragma unroll
            for (int n = 0; n < 2; n++) {
                const int ch = ((w << 1) + n) * 16 + r;
                const float bias = b2[ch];
                float v0 = LRELU(acc[m][n].x + bias);
                float v1 = LRELU(acc[m][n].y + bias);
                float v2 = LRELU(acc[m][n].z + bias);
                float v3 = LRELU(acc[m][n].w + bias);
                float v = fmaxf(fmaxf(v0, v1), fmaxf(v2, v3));
                unsigned short hi = f2bf(v);
                feat_h[s * 1664 + j * 128 + ch] = hi;
                feat_l[s * 1664 + j * 128 + ch] = f2bf(v - bf2f(hi));
            }
        }
    }
}

// ---------------------------------------------------------------------------
// MFMA projection GEMM (z-paired f/b): C = A @ W + bias. Double-buffered LDS
// A-staging via global_load_lds with raw barriers.
// ---------------------------------------------------------------------------
__global__ __launch_bounds__(256) void gemm_proj(
    const unsigned short* __restrict__ Agh, const unsigned short* __restrict__ Agl,
    const unsigned short* __restrict__ B0h, const unsigned short* __restrict__ B0l,
    const unsigned short* __restrict__ B1h, const unsigned short* __restrict__ B1l,
    const float* __restrict__ bias0, const float* __restrict__ bias1,
    float* __restrict__ C0, float* __restrict__ C1, int M, int N, int K) {
    const int z = blockIdx.z;
    const unsigned short* __restrict__ Bth = z ? B1h : B0h;
    const unsigned short* __restrict__ Btl = z ? B1l : B0l;
    const float* __restrict__ bias = z ? bias1 : bias0;
    float* __restrict__ C = z ? C1 : C0;
    __shared__ __align__(16) unsigned short Ahs[2][64 * 32];
    __shared__ __align__(16) unsigned short Als[2][64 * 32];
    const int tid = threadIdx.x;
    const int w = tid >> 6, l = tid & 63, r = l & 15, g = l >> 4;
    const int m0 = blockIdx.y * 64, n0 = blockIdx.x * 64;
    const int col = n0 + w * 16 + r;
    const int srow = tid >> 2, sgq = tid & 3;
    f32x4 acc[4];
    const f32x4 zzv = {0.f, 0.f, 0.f, 0.f};
#pragma unroll
    for (int m = 0; m < 4; m++) acc[m] = zzv;

    const long abase = (long)(m0 + srow) * K + ((sgq ^ (srow & 3)) << 3);
    auto stage = [&](int k0, int buf) {
        __builtin_amdgcn_global_load_lds(
            (const __attribute__((address_space(1))) void*)(Agh + abase + k0),
            (__attribute__((address_space(3))) void*)&Ahs[buf][tid * 8], 16, 0, 0);
        __builtin_amdgcn_global_load_lds(
            (const __attribute__((address_space(1))) void*)(Agl + abase + k0),
            (__attribute__((address_space(3))) void*)&Als[buf][tid * 8], 16, 0, 0);
    };
    stage(0, 0);
    const long bbase = (long)col * K + g * 8;
    ushort8v bhc = *(const ushort8v*)(Bth + bbase);
    ushort8v blc = *(const ushort8v*)(Btl + bbase);

    for (int k0 = 0; k0 < K; k0 += 32) {
        const int buf = (k0 >> 5) & 1;
        asm volatile("s_waitcnt vmcnt(0)" ::: "memory");
        __builtin_amdgcn_s_barrier();
        ushort8v nbh, nbl;
        if (k0 + 32 < K) {
            stage(k0 + 32, buf ^ 1);
            nbh = *(const ushort8v*)(Bth + bbase + k0 + 32);
            nbl = *(const ushort8v*)(Btl + bbase + k0 + 32);
        }
        bf16x8 bh = __builtin_bit_cast(bf16x8, bhc);
        bf16x8 bl = __builtin_bit_cast(bf16x8, blc);
#pragma unroll
        for (int m = 0; m < 4; m++) {
            const int arow = m * 16 + r;
            const int aoff = arow * 32 + ((g ^ (arow & 3)) << 3);
            bf16x8 ah = __builtin_bit_cast(bf16x8, *(const ushort8v*)(&Ahs[buf][aoff]));
            bf16x8 al = __builtin_bit_cast(bf16x8, *(const ushort8v*)(&Als[buf][aoff]));
            acc[m] = __builtin_amdgcn_mfma_f32_16x16x32_bf16(ah, bh, acc[m], 0, 0, 0);
            acc[m] = __builtin_amdgcn_mfma_f32_16x16x32_bf16(ah, bl, acc[m], 0, 0, 0);
            acc[m] = __builtin_amdgcn_mfma_f32_16x16x32_bf16(al, bh, acc[m], 0, 0, 0);
        }
        bhc = nbh;
        blc = nbl;
    }
    const float bv = bias[col];
#pragma unroll
    for (int m = 0; m < 4; m++) {
#pragma unroll
        for (int q = 0; q < 4; q++) {
            const int row = m0 + m * 16 + g * 4 + q;
            C[(long)row * N + col] = acc[m][q] + bv;
        }
    }
}

// ---------------------------------------------------------------------------
// MFMA scores GEMM: S = H @ H^T (batched), key-mask -1e9 epilogue.
// ---------------------------------------------------------------------------
__global__ __launch_bounds__(256) void gemm_scores(
    const unsigned short* __restrict__ Hh, const unsigned short* __restrict__ Hl,
    const int* __restrict__ mask, float* __restrict__ S) {
    const int bz = blockIdx.z;
    const unsigned short* __restrict__ Agh = Hh + (long)bz * 512 * 256;
    const unsigned short* __restrict__ Agl = Hl + (long)bz * 512 * 256;
    float* __restrict__ C = S + (long)bz * 512 * 512;
    const int K = 256, N = 512;
    __shared__ __align__(16) unsigned short Ahs[2][64 * 32];
    __shared__ __align__(16) unsigned short Als[2][64 * 32];
    const int tid = threadIdx.x;
    const int w = tid >> 6, l = tid & 63, r = l & 15, g = l >> 4;
    const int m0 = blockIdx.y * 64, n0 = blockIdx.x * 64;
    const int col = n0 + w * 16 + r;
    const int srow = tid >> 2, sgq = tid & 3;
    f32x4 acc[4];
    const f32x4 zzv = {0.f, 0.f, 0.f, 0.f};
#pragma unroll
    for (int m = 0; m < 4; m++) acc[m] = zzv;

    const long abase = (long)(m0 + srow) * K + ((sgq ^ (srow & 3)) << 3);
    auto stage = [&](int k0, int buf) {
        __builtin_amdgcn_global_load_lds(
            (const __attribute__((address_space(1))) void*)(Agh + abase + k0),
            (__attribute__((address_space(3))) void*)&Ahs[buf][tid * 8], 16, 0, 0);
        __builtin_amdgcn_global_load_lds(
            (const __attribute__((address_space(1))) void*)(Agl + abase + k0),
            (__attribute__((address_space(3))) void*)&Als[buf][tid * 8], 16, 0, 0);
    };
    stage(0, 0);
    const long bbase = (long)col * K + g * 8;
    ushort8v bhc = *(const ushort8v*)(Agh + bbase);
    ushort8v blc = *(const ushort8v*)(Agl + bbase);

    for (int k0 = 0; k0 < K; k0 += 32) {
        const int buf = (k0 >> 5) & 1;
        asm volatile("s_waitcnt vmcnt(0)" ::: "memory");
        __builtin_amdgcn_s_barrier();
        ushort8v nbh, nbl;
        if (k0 + 32 < K) {
            stage(k0 + 32, buf ^ 1);
            nbh = *(const ushort8v*)(Agh + bbase + k0 + 32);
            nbl = *(const ushort8v*)(Agl + bbase + k0 + 32);
        }
        bf16x8 bh = __builtin_bit_cast(bf16x8, bhc);
        bf16x8 bl = __builtin_bit_cast(bf16x8, blc);
#pragma unroll
        for (int m = 0; m < 4; m++) {
            const int arow = m * 16 + r;
            const int aoff = arow * 32 + ((g ^ (arow & 3)) << 3);
            bf16x8 ah = __builtin_bit_cast(bf16x8, *(const ushort8v*)(&Ahs[buf][aoff]));
            bf16x8 al = __builtin_bit_cast(bf16x8, *(const ushort8v*)(&Als[buf][aoff]));
            acc[m] = __builtin_amdgcn_mfma_f32_16x16x32_bf16(ah, bh, acc[m], 0, 0, 0);
            acc[m] = __builtin_amdgcn_mfma_f32_16x16x32_bf16(ah, bl, acc[m], 0, 0, 0);
            acc[m] = __builtin_amdgcn_mfma_f32_16x16x32_bf16(al, bh, acc[m], 0, 0, 0);
        }
        bhc = nbh;
        blc = nbl;
    }
    const int mk = mask[bz * 512 + col];
#pragma unroll
    for (int m = 0; m < 4; m++) {
#pragma unroll
        for (int q = 0; q < 4; q++) {
            const int row = m0 + m * 16 + g * 4 + q;
            float v = acc[m][q];
            C[(long)row * N + col] = mk ? v : -1e9f;
        }
    }
}

// ---------------------------------------------------------------------------
// Generic MFMA GEMM v3: C(hi/lo) = act(A @ B + bias).
// ---------------------------------------------------------------------------
template <int ACT>
__global__ __launch_bounds__(256) void gemm_v3(
    const unsigned short* __restrict__ Agh, const unsigned short* __restrict__ Agl,
    const unsigned short* __restrict__ Bth, const unsigned short* __restrict__ Btl,
    const float* __restrict__ bias, unsigned short* __restrict__ Ch,
    unsigned short* __restrict__ Cl, int M, int N, int K) {
    __shared__ __align__(16) unsigned short Ahs[2][64 * 32];
    __shared__ __align__(16) unsigned short Als[2][64 * 32];
    const int tid = threadIdx.x;
    const int w = tid >> 6, l = tid & 63, r = l & 15, g = l >> 4;
    const int m0 = blockIdx.y * 64, n0 = blockIdx.x * 64;
    const int col = n0 + w * 16 + r;
    const int srow = tid >> 2, sgq = tid & 3;
    f32x4 acc[4];
    const f32x4 zzv = {0.f, 0.f, 0.f, 0.f};
#pragma unroll
    for (int m = 0; m < 4; m++) acc[m] = zzv;

    const long abase = (long)(m0 + srow) * K + ((sgq ^ (srow & 3)) << 3);
    auto stage = [&](int k0, int buf) {
        __builtin_amdgcn_global_load_lds(
            (const __attribute__((address_space(1))) void*)(Agh + abase + k0),
            (__attribute__((address_space(3))) void*)&Ahs[buf][tid * 8], 16, 0, 0);
        __builtin_amdgcn_global_load_lds(
            (const __attribute__((address_space(1))) void*)(Agl + abase + k0),
            (__attribute__((address_space(3))) void*)&Als[buf][tid * 8], 16, 0, 0);
    };
    stage(0, 0);
    const long bbase = (long)col * K + g * 8;
    ushort8v bhc = *(const ushort8v*)(Bth + bbase);
    ushort8v blc = *(const ushort8v*)(Btl + bbase);

    for (int k0 = 0; k0 < K; k0 += 32) {
        const int buf = (k0 >> 5) & 1;
        asm volatile("s_waitcnt vmcnt(0)" ::: "memory");
        __builtin_amdgcn_s_barrier();
        ushort8v nbh, nbl;
        if (k0 + 32 < K) {
            stage(k0 + 32, buf ^ 1);
            nbh = *(const ushort8v*)(Bth + bbase + k0 + 32);
            nbl = *(const ushort8v*)(Btl + bbase + k0 + 32);
        }
        bf16x8 bh = __builtin_bit_cast(bf16x8, bhc);
        bf16x8 bl = __builtin_bit_cast(bf16x8, blc);
#pragma unroll
        for (int m = 0; m < 4; m++) {
            const int arow = m * 16 + r;
            const int aoff = arow * 32 + ((g ^ (arow & 3)) << 3);
            bf16x8 ah = __builtin_bit_cast(bf16x8, *(const ushort8v*)(&Ahs[buf][aoff]));
            bf16x8 al = __builtin_bit_cast(bf16x8, *(const ushort8v*)(&Als[buf][aoff]));
            acc[m] = __builtin_amdgcn_mfma_f32_16x16x32_bf16(ah, bh, acc[m], 0, 0, 0);
            acc[m] = __builtin_amdgcn_mfma_f32_16x16x32_bf16(ah, bl, acc[m], 0, 0, 0);
            acc[m] = __builtin_amdgcn_mfma_f32_16x16x32_bf16(al, bh, acc[m], 0, 0, 0);
        }
        bhc = nbh;
        blc = nbl;
    }
    const float bv = bias ? bias[col] : 0.f;
#pragma unroll
    for (int m = 0; m < 4; m++) {
#pragma unroll
        for (int q = 0; q < 4; q++) {
            const int row = m0 + m * 16 + g * 4 + q;
            float v = acc[m][q] + bv;
            if (ACT == 1) v = LRELU(v);
            unsigned short hi = f2bf(v);
            Ch[(long)row * N + col] = hi;
            Cl[(long)row * N + col] = f2bf(v - bf2f(hi));
        }
    }
}

// ---------------------------------------------------------------------------
// transpose hi/lo: out[b][d][s] = in[b][s][d]  (512 x 256 per batch)
// ---------------------------------------------------------------------------
__global__ __launch_bounds__(256) void transpose_hl(
    const unsigned short* __restrict__ inh, const unsigned short* __restrict__ inl,
    unsigned short* __restrict__ outh, unsigned short* __restrict__ outl) {
    __shared__ unsigned short th[32][33], tl[32][33];
    const int b = blockIdx.z;
    const int s0 = blockIdx.x * 32, d0 = blockIdx.y * 32;
    const unsigned short* ih = inh + (long)b * 512 * 256;
    const unsigned short* il = inl + (long)b * 512 * 256;
    unsigned short* oh = outh + (long)b * 256 * 512;
    unsigned short* ol = outl + (long)b * 256 * 512;
    const int tx = threadIdx.x & 31, ty = threadIdx.x >> 5;
#pragma unroll
    for (int i = 0; i < 4; i++) {
        int s = s0 + ty + i * 8;
        th[ty + i * 8][tx] = ih[(long)s * 256 + d0 + tx];
        tl[ty + i * 8][tx] = il[(long)s * 256 + d0 + tx];
    }
    __syncthreads();
#pragma unroll
    for (int i = 0; i < 4; i++) {
        int d = d0 + ty + i * 8;
        oh[(long)d * 512 + s0 + tx] = th[tx][ty + i * 8];
        ol[(long)d * 512 + s0 + tx] = tl[tx][ty + i * 8];
    }
}

// ---------------------------------------------------------------------------
// ctx_flash: fused softmax + ctx = softmax(S) @ H, query-mask epilogue.
// grid (8 qtiles, 1, 4 batches), 256 thr / 4 waves; wave w: 16 queries.
// Phase 1: per-row max & expsum via 64-lane shuffles (lane keeps row l&15).
// Phase 2: lane computes its own P A-fragment from fp32 S (frag row = l&15 =
// query, k = keys 8*(l>>4)+j), B = H^T (ght/glt) -> 768 MFMA/wave.
// ---------------------------------------------------------------------------
__global__ __launch_bounds__(256) void ctx_flash(
    const float* __restrict__ S, const unsigned short* __restrict__ ght,
    const unsigned short* __restrict__ glt, const int* __restrict__ mask,
    unsigned short* __restrict__ attnH, unsigned short* __restrict__ attnL) {
    const int b = blockIdx.z, qt = blockIdx.x;
    const int tid = threadIdx.x;
    const int w = tid >> 6, l = tid & 63, r = l & 15, g = l >> 4;
    const int qbase = qt * 64 + w * 16;
    const float* Sw = S + (long)b * 512 * 512 + (long)qbase * 512;

    // phase 1: row stats; lane retains stats for row r
    float mkeep = 0.f, ikeep = 0.f;
#pragma unroll 1
    for (int q = 0; q < 16; q++) {
        const float* row = Sw + (long)q * 512 + l * 8;
        float4 v0 = *(const float4*)row;
        float4 v1 = *(const float4*)(row + 4);
        float mx = fmaxf(fmaxf(fmaxf(v0.x, v0.y), fmaxf(v0.z, v0.w)),
                         fmaxf(fmaxf(v1.x, v1.y), fmaxf(v1.z, v1.w)));
#pragma unroll
        for (int off = 32; off; off >>= 1) mx = fmaxf(mx, __shfl_xor(mx, off));
        float se = exp_fast(v0.x - mx) + exp_fast(v0.y - mx) +
                   exp_fast(v0.z - mx) + exp_fast(v0.w - mx) +
                   exp_fast(v1.x - mx) + exp_fast(v1.y - mx) +
                   exp_fast(v1.z - mx) + exp_fast(v1.w - mx);
#pragma unroll
        for (int off = 32; off; off >>= 1) se += __shfl_xor(se, off);
        if (q == r) {
            mkeep = mx;
            ikeep = __builtin_amdgcn_rcpf(se);
        }
    }

    // phase 2: PV accumulate
    f32x4 o[16];
    const f32x4 zzv = {0.f, 0.f, 0.f, 0.f};
#pragma unroll
    for (int dt = 0; dt < 16; dt++) o[dt] = zzv;
    const float* Sp = S + (long)b * 512 * 512 + (long)(qbase + r) * 512;
    const unsigned short* gb = ght + (long)b * 131072;
    const unsigned short* lb = glt + (long)b * 131072;
#pragma unroll 1
    for (int kt = 0; kt < 8; kt++) {
        const int k0 = kt * 64;
        const float* pp = Sp + k0 + 8 * g;
        float4 a0 = *(const float4*)pp;
        float4 a1 = *(const float4*)(pp + 4);
        float4 a2 = *(const float4*)(pp + 32);
        float4 a3 = *(const float4*)(pp + 36);
        float pv[16] = {a0.x, a0.y, a0.z, a0.w, a1.x, a1.y, a1.z, a1.w,
                        a2.x, a2.y, a2.z, a2.w, a3.x, a3.y, a3.z, a3.w};
        ushort8v ph0, pl0, ph1, pl1;
#pragma unroll
        for (int j = 0; j < 8; j++) {
            float p = exp_fast(pv[j] - mkeep) * ikeep;
            unsigned short hi = f2bf(p);
            ph0[j] = hi;
            pl0[j] = f2bf(p - bf2f(hi));
            float p2 = exp_fast(pv[8 + j] - mkeep) * ikeep;
            unsigned short hi2 = f2bf(p2);
            ph1[j] = hi2;
            pl1[j] = f2bf(p2 - bf2f(hi2));
        }
        bf16x8 pah0 = __builtin_bit_cast(bf16x8, ph0);
        bf16x8 pal0 = __builtin_bit_cast(bf16x8, pl0);
        bf16x8 pah1 = __builtin_bit_cast(bf16x8, ph1);
        bf16x8 pal1 = __builtin_bit_cast(bf16x8, pl1);
#pragma unroll
        for (int ks2 = 0; ks2 < 2; ks2++) {
            bf16x8 pah = ks2 ? pah1 : pah0;
            bf16x8 pal = ks2 ? pal1 : pal0;
#pragma unroll
            for (int dt = 0; dt < 16; dt++) {
                const long bo = (long)(dt * 16 + r) * 512 + k0 + ks2 * 32 + 8 * g;
                bf16x8 bh = __builtin_bit_cast(bf16x8, *(const ushort8v*)(gb + bo));
                bf16x8 bl = __builtin_bit_cast(bf16x8, *(const ushort8v*)(lb + bo));
                o[dt] = __builtin_amdgcn_mfma_f32_16x16x32_bf16(pah, bh, o[dt], 0, 0, 0);
                o[dt] = __builtin_amdgcn_mfma_f32_16x16x32_bf16(pah, bl, o[dt], 0, 0, 0);
                o[dt] = __builtin_amdgcn_mfma_f32_16x16x32_bf16(pal, bh, o[dt], 0, 0, 0);
            }
        }
    }
    // epilogue: query mask, write hi/lo
#pragma unroll
    for (int reg = 0; reg < 4; reg++) {
        const int qglob = qbase + 4 * g + reg;
        const float qm = (float)mask[b * 512 + qglob];
        unsigned short* oh = attnH + ((long)(b * 512 + qglob)) * 256;
        unsigned short* ol = attnL + ((long)(b * 512 + qglob)) * 256;
#pragma unroll
        for (int dt = 0; dt < 16; dt++) {
            float v = o[dt][reg] * qm;
            unsigned short hi = f2bf(v);
            oh[dt * 16 + r] = hi;
            ol[dt * 16 + r] = f2bf(v - bf2f(hi));
        }
    }
}

// ---------------------------------------------------------------------------
// head2: fc2 = leaky(fc1 @ d2w + d2b); out = fc2 @ d3w + d3b. One block per
// 64 rows (32 blocks), 4 waves; each wave covers 4 x 16-col strips. A (fc1)
// staged once to LDS with ^(row&7) granule swizzle (pre-swizzled source).
// ---------------------------------------------------------------------------
__global__ __launch_bounds__(256) void head2_kernel(
    const unsigned short* __restrict__ fc1H, const unsigned short* __restrict__ fc1L,
    const unsigned short* __restrict__ d2th, const unsigned short* __restrict__ d2tl,
    const float* __restrict__ d2b, const float* __restrict__ d3w,
    const float* __restrict__ d3b, float* __restrict__ out) {
    __shared__ __align__(16) unsigned short Ah[64 * 256];
    __shared__ __align__(16) unsigned short Al[64 * 256];
    __shared__ float fpart[4][64];
    const int tid = threadIdx.x;
    const int w = tid >> 6, l = tid & 63, r = l & 15, g = l >> 4;
    const int m0 = blockIdx.x * 64;
    // stage A: 64 rows x 32 granules (16B), pre-swizzled source (slot^(row&7))
#pragma unroll
    for (int it = 0; it < 8; it++) {
        int gi = it * 256 + tid;
        int row = gi >> 5, slot = gi & 31;
        int scol = (slot ^ (row & 7)) * 8;
        const long so = (long)(m0 + row) * 256 + scol;
        __builtin_amdgcn_global_load_lds(
            (const __attribute__((address_space(1))) void*)(fc1H + so),
            (__attribute__((address_space(3))) void*)&Ah[gi * 8], 16, 0, 0);
        __builtin_amdgcn_global_load_lds(
            (const __attribute__((address_space(1))) void*)(fc1L + so),
            (__attribute__((address_space(3))) void*)&Al[gi * 8], 16, 0, 0);
    }
    asm volatile("s_waitcnt vmcnt(0)" ::: "memory");
    __syncthreads();

    float fs[4][4];
#pragma unroll
    for (int m = 0; m < 4; m++)
#pragma unroll
        for (int q = 0; q < 4; q++) fs[m][q] = 0.f;

#pragma unroll 1
    for (int s = 0; s < 4; s++) {
        const int col = s * 64 + w * 16 + r;
        const long bbase = (long)col * 256 + g * 8;
        f32x4 acc[4];
        const f32x4 zzv = {0.f, 0.f, 0.f, 0.f};
#pragma unroll
        for (int m = 0; m < 4; m++) acc[m] = zzv;
#pragma unroll
        for (int ks = 0; ks < 8; ks++) {
            bf16x8 bh = __builtin_bit_cast(bf16x8, *(const ushort8v*)(d2th + bbase + ks * 32));
            bf16x8 bl = __builtin_bit_cast(bf16x8, *(const ushort8v*)(d2tl + bbase + ks * 32));
#pragma unroll
            for (int m = 0; m < 4; m++) {
                const int arow = m * 16 + r;
                const int aoff = arow * 256 + (((ks * 4 + g) ^ (arow & 7)) << 3);
                bf16x8 ah = __builtin_bit_cast(bf16x8, *(const ushort8v*)(Ah + aoff));
                bf16x8 al = __builtin_bit_cast(bf16x8, *(const ushort8v*)(Al + aoff));
                acc[m] = __builtin_amdgcn_mfma_f32_16x16x32_bf16(ah, bh, acc[m], 0, 0, 0);
                acc[m] = __builtin_amdgcn_mfma_f32_16x16x32_bf16(ah, bl, acc[m], 0, 0, 0);
                acc[m] = __builtin_amdgcn_mfma_f32_16x16x32_bf16(al, bh, acc[m], 0, 0, 0);
            }
        }
        const float bv = d2b[col];
        const float w3 = d3w[col];
#pragma unroll
        for (int m = 0; m < 4; m++)
#pragma unroll
            for (int q = 0; q < 4; q++) {
                float v = LRELU(acc[m][q] + bv);
                fs[m][q] = fmaf(v, w3, fs[m][q]);
            }
    }
    // reduce across 16 col-lanes
#pragma unroll
    for (int off = 1; off < 16; off <<= 1)
#pragma unroll
        for (int m = 0; m < 4; m++)
#pragma unroll
            for (int q = 0; q < 4; q++) fs[m][q] += __shfl_xor(fs[m][q], off);
    if (r == 0) {
#pragma unroll
        for (int m = 0; m < 4; m++)
#pragma unroll
            for (int q = 0; q < 4; q++) fpart[w][m * 16 + 4 * g + q] = fs[m][q];
    }
    __syncthreads();
    if (tid < 64) {
        float tot = fpart[0][tid] + fpart[1][tid] + fpart[2][tid] +
                    fpart[3][tid] + d3b[0];
        out[m0 + tid] = tot;
    }
}

// ---------------------------------------------------------------------------
// GRU scan v7 (round-10 best-known). 8 blocks, 512 threads, thread=(c,kq).
// ---------------------------------------------------------------------------
#define D4(a0, a1, hv, uv)           \
    a0 = fmaf(hv.x, uv.x, a0);       \
    a1 = fmaf(hv.y, uv.y, a1);       \
    a0 = fmaf(hv.z, uv.z, a0);       \
    a1 = fmaf(hv.w, uv.w, a1);

__global__ __launch_bounds__(512, 2) void gru_kernel(
    const float* __restrict__ xgf, const float* __restrict__ xgb,
    const float* __restrict__ Upf, const float* __restrict__ Upb,
    const float* __restrict__ brf, const float* __restrict__ brb,
    const float* __restrict__ h0f, const float* __restrict__ h0b,
    const int* __restrict__ mask, unsigned short* __restrict__ outh,
    unsigned short* __restrict__ outl) {
    int b = blockIdx.x & 3;
    int dir = blockIdx.x >> 2;
    const float* __restrict__ xg = dir ? xgb : xgf;
    const float* __restrict__ Up = dir ? Upb : Upf;
    const float* __restrict__ br = dir ? brb : brf;
    const float* __restrict__ h0 = dir ? h0b : h0f;
    const int tid = threadIdx.x;
    const int c = tid >> 2;   // column 0..127
    const int kq = tid & 3;   // k-quad

    __shared__ __align__(16) float xs[2][16 * 384];
    __shared__ __align__(16) float hsh[2][144];
    __shared__ __align__(16) unsigned int histp[16][128];
    __shared__ unsigned long long mwords[8];

    auto stage = [&](int cc, int bufi) {
#pragma unroll
        for (int i = 0; i < 3; i++) {
            int g = i * 512 + tid;
            int j = g / 96;
            int col = (g - j * 96) * 4;
            int ts = cc * 16 + j;
            int t = dir ? (511 - ts) : ts;
            const float* src = xg + ((long)(b * 512 + t)) * 384 + col;
            __builtin_amdgcn_global_load_lds(
                (const __attribute__((address_space(1))) void*)src,
                (__attribute__((address_space(3))) void*)&xs[bufi][g * 4], 16, 0, 0);
        }
    };
    stage(0, 0);

    const float* ub = Up + (tid << 2);
    f32x4 uz0 = *(const f32x4*)(ub + 0 * 2048);
    f32x4 uz1 = *(const f32x4*)(ub + 1 * 2048);
    f32x4 uz2 = *(const f32x4*)(ub + 2 * 2048);
    f32x4 uz3 = *(const f32x4*)(ub + 3 * 2048);
    f32x4 uz4 = *(const f32x4*)(ub + 4 * 2048);
    f32x4 uz5 = *(const f32x4*)(ub + 5 * 2048);
    f32x4 uz6 = *(const f32x4*)(ub + 6 * 2048);
    f32x4 uz7 = *(const f32x4*)(ub + 7 * 2048);
    f32x4 ur0 = *(const f32x4*)(ub + 8 * 2048);
    f32x4 ur1 = *(const f32x4*)(ub + 9 * 2048);
    f32x4 ur2 = *(const f32x4*)(ub + 10 * 2048);
    f32x4 ur3 = *(const f32x4*)(ub + 11 * 2048);
    f32x4 ur4 = *(const f32x4*)(ub + 12 * 2048);
    f32x4 ur5 = *(const f32x4*)(ub + 13 * 2048);
    f32x4 ur6 = *(const f32x4*)(ub + 14 * 2048);
    f32x4 ur7 = *(const f32x4*)(ub + 15 * 2048);
    f32x4 uh0 = *(const f32x4*)(ub + 16 * 2048);
    f32x4 uh1 = *(const f32x4*)(ub + 17 * 2048);
    f32x4 uh2 = *(const f32x4*)(ub + 18 * 2048);
    f32x4 uh3 = *(const f32x4*)(ub + 19 * 2048);
    f32x4 uh4 = *(const f32x4*)(ub + 20 * 2048);
    f32x4 uh5 = *(const f32x4*)(ub + 21 * 2048);
    f32x4 uh6 = *(const f32x4*)(ub + 22 * 2048);
    f32x4 uh7 = *(const f32x4*)(ub + 23 * 2048);

    float br3[3];
#pragma unroll
    for (int g = 0; g < 3; g++) br3[g] = br[g * 128 + c];

    float hreg = h0[b * 128 + c];
    if (kq == 0) hsh[0][c + (c >> 5) * 4] = hreg;
    if (tid < 64) {
#pragma unroll
        for (int w = 0; w < 8; w++) {
            int idx = w * 64 + tid;
            int t = dir ? (511 - idx) : idx;
            unsigned long long bm = __ballot(mask[b * 512 + t] != 0);
            if (tid == 0) mwords[w] = bm;
        }
    }
    asm volatile("s_waitcnt lgkmcnt(0)" ::: "memory");
    __builtin_amdgcn_s_barrier();

    int cur = 0;
    for (int cc = 0; cc < 32; cc++) {
        asm volatile("s_waitcnt vmcnt(0)" ::: "memory");
        if (cc < 31) stage(cc + 1, (cc + 1) & 1);
        __builtin_amdgcn_s_barrier();
        const float* xb = xs[cc & 1];
        unsigned mwbits = (unsigned)((mwords[cc >> 2] >> ((cc & 3) * 16)) & 0xffffull);
#pragma unroll 1
        for (int jj = 0; jj < 16; jj++) {
            if ((mwbits >> jj) & 1) {
                const float* hp = &hsh[cur][kq * 36];
                float4 h0v = *(const float4*)(hp + 0);
                float4 h1v = *(const float4*)(hp + 4);
                float4 h2v = *(const float4*)(hp + 8);
                float4 h3v = *(const float4*)(hp + 12);
                float4 h4v = *(const float4*)(hp + 16);
                float4 h5v = *(const float4*)(hp + 20);
                float4 h6v = *(const float4*)(hp + 24);
                float4 h7v = *(const float4*)(hp + 28);
                float az0 = 0.f, az1 = 0.f, ar0 = 0.f, ar1 = 0.f, ah0 = 0.f, ah1 = 0.f;
                D4(az0, az1, h0v, uz0) D4(az0, az1, h1v, uz1)
                D4(az0, az1, h2v, uz2) D4(az0, az1, h3v, uz3)
                D4(az0, az1, h4v, uz4) D4(az0, az1, h5v, uz5)
                D4(az0, az1, h6v, uz6) D4(az0, az1, h7v, uz7)
                D4(ar0, ar1, h0v, ur0) D4(ar0, ar1, h1v, ur1)
                D4(ar0, ar1, h2v, ur2) D4(ar0, ar1, h3v, ur3)
                D4(ar0, ar1, h4v, ur4) D4(ar0, ar1, h5v, ur5)
                D4(ar0, ar1, h6v, ur6) D4(ar0, ar1, h7v, ur7)
                D4(ah0, ah1, h0v, uh0) D4(ah0, ah1, h1v, uh1)
                D4(ah0, ah1, h2v, uh2) D4(ah0, ah1, h3v, uh3)
                D4(ah0, ah1, h4v, uh4) D4(ah0, ah1, h5v, uh5)
                D4(ah0, ah1, h6v, uh6) D4(ah0, ah1, h7v, uh7)
                float rgz = dpp_add_xor2(dpp_add_xor1(az0 + az1));
                float rgr = dpp_add_xor2(dpp_add_xor1(ar0 + ar1));
                float rgh = dpp_add_xor2(dpp_add_xor1(ah0 + ah1));
                if (kq == 0) {
                    float xz = xb[jj * 384 + c];
                    float xr = xb[jj * 384 + 128 + c];
                    float xh = xb[jj * 384 + 256 + c];
                    float z = sigmoid_fast(xz + rgz + br3[0]);
                    float r_ = sigmoid_fast(xr + rgr + br3[1]);
                    float hc = tanh_fast(fmaf(r_, rgh + br3[2], xh));
                    float hn = fmaf(z, hreg - hc, hc);
                    hreg = hn;
                    hsh[cur ^ 1][c + (c >> 5) * 4] = hn;
                    unsigned short hh = f2bf(hn);
                    histp[jj][c] = (unsigned)hh |
                                   ((unsigned)f2bf(hn - bf2f(hh)) << 16);
                }
                asm volatile("s_waitcnt lgkmcnt(0)" ::: "memory");
                __builtin_amdgcn_s_barrier();
                cur ^= 1;
            } else {
                if (kq == 0) {
                    unsigned short hh = f2bf(hreg);
                    histp[jj][c] = (unsigned)hh |
                                   ((unsigned)f2bf(hreg - bf2f(hh)) << 16);
                }
            }
        }
        asm volatile("s_waitcnt lgkmcnt(0)" ::: "memory");
        __builtin_amdgcn_s_barrier();
        {
            int fj = tid >> 5, fc = (tid & 31) << 2;
            int ts2 = cc * 16 + fj;
            int tf = dir ? (511 - ts2) : ts2;
            long ob = ((long)(b * 512 + tf)) * 256 + dir * 128 + fc;
            uint4 hp4 = *(const uint4*)&histp[fj][fc];
            u32x2 ph, pl;
            ph.x = (hp4.x & 0xffffu) | (hp4.y << 16);
            ph.y = (hp4.z & 0xffffu) | (hp4.w << 16);
            pl.x = (hp4.x >> 16) | (hp4.y & 0xffff0000u);
            pl.y = (hp4.z >> 16) | (hp4.w & 0xffff0000u);
            *(u32x2*)(outh + ob) = ph;
            *(u32x2*)(outl + ob) = pl;
        }
    }
}

// ---------------------------------------------------------------------------
extern "C" void kernel_launch(void* const* d_in, const int* in_sizes, int n_in,
                              void* d_out, int out_size, void* d_ws,
                              size_t ws_size, hipStream_t stream) {
    const float* x = (const float*)d_in[0];
    const unsigned int* mraw = (const unsigned int*)d_in[1];
    const float* s1f = (const float*)d_in[2];
    const float* s1b = (const float*)d_in[3];
    const float* s2f = (const float*)d_in[4];
    const float* s2b = (const float*)d_in[5];
    const float* c1w = (const float*)d_in[6];
    const float* c1b = (const float*)d_in[7];
    const float* c2w = (const float*)d_in[8];
    const float* c2b = (const float*)d_in[9];
    const float* g1fW = (const float*)d_in[10];
    const float* g1fU = (const float*)d_in[11];
    const float* g1fb = (const float*)d_in[12];
    const float* g1bW = (const float*)d_in[13];
    const float* g1bU = (const float*)d_in[14];
    const float* g1bb = (const float*)d_in[15];
    const float* g2fW = (const float*)d_in[16];
    const float* g2fU = (const float*)d_in[17];
    const float* g2fb = (const float*)d_in[18];
    const float* g2bW = (const float*)d_in[19];
    const float* g2bU = (const float*)d_in[20];
    const float* g2bb = (const float*)d_in[21];
    const float* d1w = (const float*)d_in[22];
    const float* d1b = (const float*)d_in[23];
    const float* d2w = (const float*)d_in[24];
    const float* d2b = (const float*)d_in[25];
    const float* d3w = (const float*)d_in[26];
    const float* d3b = (const float*)d_in[27];
    float* out = (float*)d_out;

    float* ws = (float*)d_ws;
    size_t off = 0;
    auto take = [&](size_t n) {  // n in floats
        float* p = ws + off;
        off += (n + 63) & ~(size_t)63;
        return p;
    };
    int* mask_i = (int*)take(2048);
    unsigned short* feat_h = (unsigned short*)take(2048UL * 1664 / 2);
    unsigned short* feat_l = (unsigned short*)take(2048UL * 1664 / 2);
    float* xg1f = take(2048UL * 384);
    float* xg1b = take(2048UL * 384);
    unsigned short* gru1h = (unsigned short*)take(2048UL * 128);
    unsigned short* gru1l = (unsigned short*)take(2048UL * 128);
    float* xg2f = take(2048UL * 384);
    float* xg2b = take(2048UL * 384);
    unsigned short* gru2h = (unsigned short*)take(2048UL * 128);
    unsigned short* gru2l = (unsigned short*)take(2048UL * 128);
    unsigned short* ght = (unsigned short*)take(2048UL * 128);
    unsigned short* glt = (unsigned short*)take(2048UL * 128);
    float* sc = take(4UL * 512 * 512);
    unsigned short* attnH = (unsigned short*)take(2048UL * 128);
    unsigned short* attnL = (unsigned short*)take(2048UL * 128);
    unsigned short* fc1H = (unsigned short*)take(2048UL * 128);
    unsigned short* fc1L = (unsigned short*)take(2048UL * 128);
    unsigned short* bth = (unsigned short*)take(65536);
    unsigned short* btl = (unsigned short*)take(65536);
    unsigned short* wt1fh = (unsigned short*)take(319488);
    unsigned short* wt1fl = (unsigned short*)take(319488);
    unsigned short* wt1bh = (unsigned short*)take(319488);
    unsigned short* wt1bl = (unsigned short*)take(319488);
    unsigned short* wt2fh = (unsigned short*)take(49152);
    unsigned short* wt2fl = (unsigned short*)take(49152);
    unsigned short* wt2bh = (unsigned short*)take(49152);
    unsigned short* wt2bl = (unsigned short*)take(49152);
    unsigned short* d1th = (unsigned short*)take(32768);
    unsigned short* d1tl = (unsigned short*)take(32768);
    unsigned short* d2th = (unsigned short*)take(32768);
    unsigned short* d2tl = (unsigned short*)take(32768);
    float* up1f = take(49152);
    float* up1b = take(49152);
    float* up2f = take(49152);
    float* up2b = take(49152);

    prepack_all<<<7553, 256, 0, stream>>>(
        c2w, bth, btl, g1fW, wt1fh, wt1fl, g1bW, wt1bh, wt1bl, g2fW, wt2fh,
        wt2fl, g2bW, wt2bh, wt2bl, g1fU, up1f, g1bU, up1b, g2fU, up2f, g2bU,
        up2b, d1w, d1th, d1tl, d2w, d2th, d2tl, mraw, mask_i);
    conv_kernel<<<2048, 256, 0, stream>>>(x, c1w, c1b, bth, btl, c2b, feat_h, feat_l);

    gemm_proj<<<dim3(6, 32, 2), 256, 0, stream>>>(
        feat_h, feat_l, wt1fh, wt1fl, wt1bh, wt1bl, g1fb, g1bb, xg1f, xg1b,
        2048, 384, 1664);
    gru_kernel<<<8, 512, 0, stream>>>(xg1f, xg1b, up1f, up1b, g1fb + 384,
                                      g1bb + 384, s1f, s1b, mask_i, gru1h, gru1l);

    gemm_proj<<<dim3(6, 32, 2), 256, 0, stream>>>(
        gru1h, gru1l, wt2fh, wt2fl, wt2bh, wt2bl, g2fb, g2bb, xg2f, xg2b,
        2048, 384, 256);
    gru_kernel<<<8, 512, 0, stream>>>(xg2f, xg2b, up2f, up2b, g2fb + 384,
                                      g2bb + 384, s2f, s2b, mask_i, gru2h, gru2l);

    transpose_hl<<<dim3(16, 8, 4), 256, 0, stream>>>(gru2h, gru2l, ght, glt);
    gemm_scores<<<dim3(8, 8, 4), 256, 0, stream>>>(gru2h, gru2l, mask_i, sc);
    ctx_flash<<<dim3(8, 1, 4), 256, 0, stream>>>(sc, ght, glt, mask_i, attnH, attnL);
    gemm_v3<1><<<dim3(4, 32, 1), 256, 0, stream>>>(
        attnH, attnL, d1th, d1tl, d1b, fc1H, fc1L, 2048, 256, 256);
    head2_kernel<<<32, 256, 0, stream>>>(fc1H, fc1L, d2th, d2tl, d2b, d3w,
                                         d3b, out);
}

// Round 16
// 629.755 us; speedup vs baseline: 1.1355x; 1.1355x over previous
//
#include <hip/hip_runtime.h>

#define LRELU(v) ((v) > 0.f ? (v) : 0.2f * (v))

typedef float f32x4 __attribute__((ext_vector_type(4)));
typedef __bf16 bf16x8 __attribute__((ext_vector_type(8)));
typedef unsigned short ushort8v __attribute__((ext_vector_type(8)));
typedef unsigned int u32x2 __attribute__((ext_vector_type(2)));

__device__ __forceinline__ unsigned short f2bf(float f) {
    unsigned int u = __float_as_uint(f);
    u += 0x7fffu + ((u >> 16) & 1u);
    return (unsigned short)(u >> 16);
}
__device__ __forceinline__ float bf2f(unsigned short h) {
    return __uint_as_float(((unsigned int)h) << 16);
}
__device__ __forceinline__ float sigmoid_fast(float x) {
    float e = __builtin_amdgcn_exp2f(-x * 1.442695041f);
    return __builtin_amdgcn_rcpf(1.f + e);
}
__device__ __forceinline__ float tanh_fast(float x) {
    float e = __builtin_amdgcn_exp2f(x * 2.885390082f);  // e^(2x)
    return 1.f - 2.f * __builtin_amdgcn_rcpf(e + 1.f);
}
// quad_perm DPP adds (VALU pipe)
__device__ __forceinline__ float dpp_add_xor1(float v) {
    int r = __builtin_amdgcn_mov_dpp(__float_as_int(v), 0xB1, 0xF, 0xF, true);
    return v + __int_as_float(r);
}
__device__ __forceinline__ float dpp_add_xor2(float v) {
    int r = __builtin_amdgcn_mov_dpp(__float_as_int(v), 0x4E, 0xF, 0xF, true);
    return v + __int_as_float(r);
}

// ---------------------------------------------------------------------------
// ONE prepack kernel: all weight transforms + mask decode, segmented by block.
// ---------------------------------------------------------------------------
__device__ __forceinline__ void wtpack(const float* __restrict__ W,
                                       unsigned short* __restrict__ h,
                                       unsigned short* __restrict__ l, int K,
                                       int N, long idx) {
    int n = (int)(idx / K), k = (int)(idx % K);
    float v = W[(long)k * N + n];
    unsigned short hi = f2bf(v);
    h[idx] = hi;
    l[idx] = f2bf(v - bf2f(hi));
}
// lane-coalesced quad layout (round-10): up[(g*8+q)*2048 + t*4 + i]
__device__ __forceinline__ void ugpack(const float* __restrict__ U,
                                       float* __restrict__ up, int widx) {
    int quad = widx >> 11;
    int rem = widx & 2047;
    int t = rem >> 2, i = rem & 3;
    int g = quad >> 3, q = quad & 7;
    int c = t >> 2, kq = t & 3;
    up[widx] = U[(long)(kq * 32 + q * 4 + i) * 384 + g * 128 + c];
}

__global__ __launch_bounds__(256) void prepack_all(
    const float* __restrict__ w2, unsigned short* __restrict__ bth,
    unsigned short* __restrict__ btl, const float* __restrict__ g1fW,
    unsigned short* __restrict__ wt1fh, unsigned short* __restrict__ wt1fl,
    const float* __restrict__ g1bW, unsigned short* __restrict__ wt1bh,
    unsigned short* __restrict__ wt1bl, const float* __restrict__ g2fW,
    unsigned short* __restrict__ wt2fh, unsigned short* __restrict__ wt2fl,
    const float* __restrict__ g2bW, unsigned short* __restrict__ wt2bh,
    unsigned short* __restrict__ wt2bl, const float* __restrict__ g1fU,
    float* __restrict__ up1f, const float* __restrict__ g1bU,
    float* __restrict__ up1b, const float* __restrict__ g2fU,
    float* __restrict__ up2f, const float* __restrict__ g2bU,
    float* __restrict__ up2b, const float* __restrict__ d1w,
    unsigned short* __restrict__ d1th, unsigned short* __restrict__ d1tl,
    const float* __restrict__ d2w, unsigned short* __restrict__ d2th,
    unsigned short* __restrict__ d2tl, const unsigned int* __restrict__ mraw,
    int* __restrict__ mi) {
    const int bid = blockIdx.x, tid = threadIdx.x;
    if (bid < 512) {
        int idx = bid * 256 + tid;
        int c = idx >> 10, k = idx & 1023;
        float v = w2[k * 128 + c];
        unsigned short hi = f2bf(v);
        bth[(long)c * 1024 + k] = hi;
        btl[(long)c * 1024 + k] = f2bf(v - bf2f(hi));
    } else if (bid < 3008) {
        wtpack(g1fW, wt1fh, wt1fl, 1664, 384, (long)(bid - 512) * 256 + tid);
    } else if (bid < 5504) {
        wtpack(g1bW, wt1bh, wt1bl, 1664, 384, (long)(bid - 3008) * 256 + tid);
    } else if (bid < 5888) {
        wtpack(g2fW, wt2fh, wt2fl, 256, 384, (long)(bid - 5504) * 256 + tid);
    } else if (bid < 6272) {
        wtpack(g2bW, wt2bh, wt2bl, 256, 384, (long)(bid - 5888) * 256 + tid);
    } else if (bid < 6464) {
        ugpack(g1fU, up1f, (bid - 6272) * 256 + tid);
    } else if (bid < 6656) {
        ugpack(g1bU, up1b, (bid - 6464) * 256 + tid);
    } else if (bid < 6848) {
        ugpack(g2fU, up2f, (bid - 6656) * 256 + tid);
    } else if (bid < 7040) {
        ugpack(g2bU, up2b, (bid - 6848) * 256 + tid);
    } else if (bid < 7296) {
        wtpack(d1w, d1th, d1tl, 256, 256, (long)(bid - 7040) * 256 + tid);
    } else if (bid < 7552) {
        wtpack(d2w, d2th, d2tl, 256, 256, (long)(bid - 7296) * 256 + tid);
    } else {
        __shared__ int flag;
        if (tid == 0) flag = 0;
        __syncthreads();
        unsigned a = mraw[tid * 2], bb = mraw[tid * 2 + 1];
        if (a > 1u || bb > 1u) flag = 1;
        __syncthreads();
        if (flag) {
            const unsigned char* b8 = (const unsigned char*)mraw;
            for (int i = tid; i < 2048; i += 256) mi[i] = b8[i] ? 1 : 0;
        } else {
            for (int i = tid; i < 2048; i += 256) mi[i] = mraw[i] ? 1 : 0;
        }
    }
}

// ---------------------------------------------------------------------------
// Fused conv1(fp32)+pool1 -> LDS bf16 hi/lo -> conv2 via split-bf16 MFMA +
// fused leaky+pool2. One block (256 thr, 4 waves) per sequence.
// ---------------------------------------------------------------------------
__global__ __launch_bounds__(256) void conv_kernel(
    const float* __restrict__ x, const float* __restrict__ w1,
    const float* __restrict__ b1, const unsigned short* __restrict__ bth,
    const unsigned short* __restrict__ btl, const float* __restrict__ b2,
    unsigned short* __restrict__ feat_h, unsigned short* __restrict__ feat_l) {
    __shared__ float xs[3][256];
    __shared__ __align__(16) unsigned short p1h[72 * 128];
    __shared__ __align__(16) unsigned short p1l[72 * 128];
    long s = blockIdx.x;
    int tid = threadIdx.x;
    const float* xp = x + s * 768;
    for (int i = tid; i < 768; i += 256) xs[i % 3][i / 3] = xp[i];
    for (int i = tid; i < 10 * 128; i += 256) {
        p1h[62 * 128 + i] = 0;
        p1l[62 * 128 + i] = 0;
    }
    __syncthreads();

    {   // conv1 + pool1, fp32, swizzled bf16 hi/lo store
        int ch = tid & 127;
        int half = tid >> 7;
        float w1r[24];
#pragma unroll
        for (int fc = 0; fc < 24; fc++) w1r[fc] = w1[fc * 128 + ch];
        float bias1 = b1[ch];
        for (int po = half; po < 62; po += 2) {
            int p0 = po * 4;
            float a0 = bias1, a1 = bias1, a2 = bias1, a3 = bias1;
#pragma unroll
            for (int c = 0; c < 3; c++) {
                float xv[11];
#pragma unroll
                for (int q = 0; q < 11; q++) xv[q] = xs[c][p0 + q];
#pragma unroll
                for (int f = 0; f < 8; f++) {
                    float w = w1r[f * 3 + c];
                    a0 = fmaf(xv[f + 0], w, a0);
                    a1 = fmaf(xv[f + 1], w, a1);
                    a2 = fmaf(xv[f + 2], w, a2);
                    a3 = fmaf(xv[f + 3], w, a3);
                }
            }
            float m01 = fmaxf(LRELU(a0), LRELU(a1));
            float m23 = fmaxf(LRELU(a2), LRELU(a3));
            float v = fmaxf(m01, m23);
            unsigned short hi = f2bf(v);
            unsigned short lo = f2bf(v - bf2f(hi));
            int cs = ch ^ ((po & 7) << 3);
            p1h[po * 128 + cs] = hi;
            p1l[po * 128 + cs] = lo;
        }
    }
    __syncthreads();

    const int l = tid & 63, w = tid >> 6;
    const int r = l & 15, g = l >> 4;
    f32x4 acc[4][2];
    const f32x4 zz = {0.f, 0.f, 0.f, 0.f};
#pragma unroll
    for (int m = 0; m < 4; m++) {
        acc[m][0] = zz;
        acc[m][1] = zz;
    }
#pragma unroll 2
    for (int ks = 0; ks < 32; ks++) {
        const int f = ks >> 2;
        const int cin0 = ((ks & 3) << 5) + (g << 3);
        bf16x8 bh[2], bl[2];
#pragma unroll
        for (int n = 0; n < 2; n++) {
            const int c = ((w << 1) + n) * 16 + r;
            const long bo = (long)c * 1024 + (ks << 5) + (g << 3);
            bh[n] = __builtin_bit_cast(bf16x8, *(const ushort8v*)(bth + bo));
            bl[n] = __builtin_bit_cast(bf16x8, *(const ushort8v*)(btl + bo));
        }
        bf16x8 ah[4], al[4];
#pragma unroll
        for (int m = 0; m < 4; m++) {
            const int row = m * 16 + r + f;
            const int col = cin0 ^ ((row & 7) << 3);
            const int off = row * 128 + col;
            ah[m] = __builtin_bit_cast(bf16x8, *(const ushort8v*)(p1h + off));
            al[m] = __builtin_bit_cast(bf16x8, *(const ushort8v*)(p1l + off));
        }
#pragma unroll
        for (int m = 0; m < 4; m++) {
#pragma unroll
            for (int n = 0; n < 2; n++) {
                acc[m][n] = __builtin_amdgcn_mfma_f32_16x16x32_bf16(ah[m], bh[n], acc[m][n], 0, 0, 0);
                acc[m][n] = __builtin_amdgcn_mfma_f32_16x16x32_bf16(ah[m], bl[n], acc[m][n], 0, 0, 0);
                acc[m][n] = __builtin_amdgcn_mfma_f32_16x16x32_bf16(al[m], bh[n], acc[m][n], 0, 0, 0);
            }
        }
    }
#pragma unroll
    for (int m = 0; m < 4; m++) {
        const int j = m * 4 + g;
        if (j < 13) {
#pragma unroll
            for (int n = 0; n < 2; n++) {
                const int ch = ((w << 1) + n) * 16 + r;
                const float bias = b2[ch];
                float v0 = LRELU(acc[m][n].x + bias);
                float v1 = LRELU(acc[m][n].y + bias);
                float v2 = LRELU(acc[m][n].z + bias);
                float v3 = LRELU(acc[m][n].w + bias);
                float v = fmaxf(fmaxf(v0, v1), fmaxf(v2, v3));
                unsigned short hi = f2bf(v);
                feat_h[s * 1664 + j * 128 + ch] = hi;
                feat_l[s * 1664 + j * 128 + ch] = f2bf(v - bf2f(hi));
            }
        }
    }
}

// ---------------------------------------------------------------------------
// MFMA projection GEMM (z-paired f/b): C = A @ W + bias. Double-buffered LDS
// A-staging via global_load_lds with raw barriers.
// ---------------------------------------------------------------------------
__global__ __launch_bounds__(256) void gemm_proj(
    const unsigned short* __restrict__ Agh, const unsigned short* __restrict__ Agl,
    const unsigned short* __restrict__ B0h, const unsigned short* __restrict__ B0l,
    const unsigned short* __restrict__ B1h, const unsigned short* __restrict__ B1l,
    const float* __restrict__ bias0, const float* __restrict__ bias1,
    float* __restrict__ C0, float* __restrict__ C1, int M, int N, int K) {
    const int z = blockIdx.z;
    const unsigned short* __restrict__ Bth = z ? B1h : B0h;
    const unsigned short* __restrict__ Btl = z ? B1l : B0l;
    const float* __restrict__ bias = z ? bias1 : bias0;
    float* __restrict__ C = z ? C1 : C0;
    __shared__ __align__(16) unsigned short Ahs[2][64 * 32];
    __shared__ __align__(16) unsigned short Als[2][64 * 32];
    const int tid = threadIdx.x;
    const int w = tid >> 6, l = tid & 63, r = l & 15, g = l >> 4;
    const int m0 = blockIdx.y * 64, n0 = blockIdx.x * 64;
    const int col = n0 + w * 16 + r;
    const int srow = tid >> 2, sgq = tid & 3;
    f32x4 acc[4];
    const f32x4 zzv = {0.f, 0.f, 0.f, 0.f};
#pragma unroll
    for (int m = 0; m < 4; m++) acc[m] = zzv;

    const long abase = (long)(m0 + srow) * K + ((sgq ^ (srow & 3)) << 3);
    auto stage = [&](int k0, int buf) {
        __builtin_amdgcn_global_load_lds(
            (const __attribute__((address_space(1))) void*)(Agh + abase + k0),
            (__attribute__((address_space(3))) void*)&Ahs[buf][tid * 8], 16, 0, 0);
        __builtin_amdgcn_global_load_lds(
            (const __attribute__((address_space(1))) void*)(Agl + abase + k0),
            (__attribute__((address_space(3))) void*)&Als[buf][tid * 8], 16, 0, 0);
    };
    stage(0, 0);
    const long bbase = (long)col * K + g * 8;
    ushort8v bhc = *(const ushort8v*)(Bth + bbase);
    ushort8v blc = *(const ushort8v*)(Btl + bbase);

    for (int k0 = 0; k0 < K; k0 += 32) {
        const int buf = (k0 >> 5) & 1;
        asm volatile("s_waitcnt vmcnt(0)" ::: "memory");
        __builtin_amdgcn_s_barrier();
        ushort8v nbh, nbl;
        if (k0 + 32 < K) {
            stage(k0 + 32, buf ^ 1);
            nbh = *(const ushort8v*)(Bth + bbase + k0 + 32);
            nbl = *(const ushort8v*)(Btl + bbase + k0 + 32);
        }
        bf16x8 bh = __builtin_bit_cast(bf16x8, bhc);
        bf16x8 bl = __builtin_bit_cast(bf16x8, blc);
#pragma unroll
        for (int m = 0; m < 4; m++) {
            const int arow = m * 16 + r;
            const int aoff = arow * 32 + ((g ^ (arow & 3)) << 3);
            bf16x8 ah = __builtin_bit_cast(bf16x8, *(const ushort8v*)(&Ahs[buf][aoff]));
            bf16x8 al = __builtin_bit_cast(bf16x8, *(const ushort8v*)(&Als[buf][aoff]));
            acc[m] = __builtin_amdgcn_mfma_f32_16x16x32_bf16(ah, bh, acc[m], 0, 0, 0);
            acc[m] = __builtin_amdgcn_mfma_f32_16x16x32_bf16(ah, bl, acc[m], 0, 0, 0);
            acc[m] = __builtin_amdgcn_mfma_f32_16x16x32_bf16(al, bh, acc[m], 0, 0, 0);
        }
        bhc = nbh;
        blc = nbl;
    }
    const float bv = bias[col];
#pragma unroll
    for (int m = 0; m < 4; m++) {
#pragma unroll
        for (int q = 0; q < 4; q++) {
            const int row = m0 + m * 16 + g * 4 + q;
            C[(long)row * N + col] = acc[m][q] + bv;
        }
    }
}

// ---------------------------------------------------------------------------
// MFMA scores GEMM: S = H @ H^T (batched), key-mask -1e9 epilogue.
// ---------------------------------------------------------------------------
__global__ __launch_bounds__(256) void gemm_scores(
    const unsigned short* __restrict__ Hh, const unsigned short* __restrict__ Hl,
    const int* __restrict__ mask, float* __restrict__ S) {
    const int bz = blockIdx.z;
    const unsigned short* __restrict__ Agh = Hh + (long)bz * 512 * 256;
    const unsigned short* __restrict__ Agl = Hl + (long)bz * 512 * 256;
    float* __restrict__ C = S + (long)bz * 512 * 512;
    const int K = 256, N = 512;
    __shared__ __align__(16) unsigned short Ahs[2][64 * 32];
    __shared__ __align__(16) unsigned short Als[2][64 * 32];
    const int tid = threadIdx.x;
    const int w = tid >> 6, l = tid & 63, r = l & 15, g = l >> 4;
    const int m0 = blockIdx.y * 64, n0 = blockIdx.x * 64;
    const int col = n0 + w * 16 + r;
    const int srow = tid >> 2, sgq = tid & 3;
    f32x4 acc[4];
    const f32x4 zzv = {0.f, 0.f, 0.f, 0.f};
#pragma unroll
    for (int m = 0; m < 4; m++) acc[m] = zzv;

    const long abase = (long)(m0 + srow) * K + ((sgq ^ (srow & 3)) << 3);
    auto stage = [&](int k0, int buf) {
        __builtin_amdgcn_global_load_lds(
            (const __attribute__((address_space(1))) void*)(Agh + abase + k0),
            (__attribute__((address_space(3))) void*)&Ahs[buf][tid * 8], 16, 0, 0);
        __builtin_amdgcn_global_load_lds(
            (const __attribute__((address_space(1))) void*)(Agl + abase + k0),
            (__attribute__((address_space(3))) void*)&Als[buf][tid * 8], 16, 0, 0);
    };
    stage(0, 0);
    const long bbase = (long)col * K + g * 8;
    ushort8v bhc = *(const ushort8v*)(Agh + bbase);
    ushort8v blc = *(const ushort8v*)(Agl + bbase);

    for (int k0 = 0; k0 < K; k0 += 32) {
        const int buf = (k0 >> 5) & 1;
        asm volatile("s_waitcnt vmcnt(0)" ::: "memory");
        __builtin_amdgcn_s_barrier();
        ushort8v nbh, nbl;
        if (k0 + 32 < K) {
            stage(k0 + 32, buf ^ 1);
            nbh = *(const ushort8v*)(Agh + bbase + k0 + 32);
            nbl = *(const ushort8v*)(Agl + bbase + k0 + 32);
        }
        bf16x8 bh = __builtin_bit_cast(bf16x8, bhc);
        bf16x8 bl = __builtin_bit_cast(bf16x8, blc);
#pragma unroll
        for (int m = 0; m < 4; m++) {
            const int arow = m * 16 + r;
            const int aoff = arow * 32 + ((g ^ (arow & 3)) << 3);
            bf16x8 ah = __builtin_bit_cast(bf16x8, *(const ushort8v*)(&Ahs[buf][aoff]));
            bf16x8 al = __builtin_bit_cast(bf16x8, *(const ushort8v*)(&Als[buf][aoff]));
            acc[m] = __builtin_amdgcn_mfma_f32_16x16x32_bf16(ah, bh, acc[m], 0, 0, 0);
            acc[m] = __builtin_amdgcn_mfma_f32_16x16x32_bf16(ah, bl, acc[m], 0, 0, 0);
            acc[m] = __builtin_amdgcn_mfma_f32_16x16x32_bf16(al, bh, acc[m], 0, 0, 0);
        }
        bhc = nbh;
        blc = nbl;
    }
    const int mk = mask[bz * 512 + col];
#pragma unroll
    for (int m = 0; m < 4; m++) {
#pragma unroll
        for (int q = 0; q < 4; q++) {
            const int row = m0 + m * 16 + g * 4 + q;
            float v = acc[m][q];
            C[(long)row * N + col] = mk ? v : -1e9f;
        }
    }
}

// ---------------------------------------------------------------------------
// Generic MFMA GEMM v3: C(hi/lo) = [qmask*] act(A @ B + bias). Pre-split
// hi/lo A (M,K) and B^T (N,K); batched via element strides.
// ---------------------------------------------------------------------------
template <int ACT, int QMASK>
__global__ __launch_bounds__(256) void gemm_v3(
    const unsigned short* __restrict__ Agh, const unsigned short* __restrict__ Agl,
    const unsigned short* __restrict__ Bth, const unsigned short* __restrict__ Btl,
    const float* __restrict__ bias, const int* __restrict__ qmask,
    unsigned short* __restrict__ Ch, unsigned short* __restrict__ Cl,
    long sA, long sB, long sC, int M, int N, int K) {
    const int bz = blockIdx.z;
    Agh += (long)bz * sA;
    Agl += (long)bz * sA;
    Bth += (long)bz * sB;
    Btl += (long)bz * sB;
    Ch += (long)bz * sC;
    Cl += (long)bz * sC;
    __shared__ __align__(16) unsigned short Ahs[2][64 * 32];
    __shared__ __align__(16) unsigned short Als[2][64 * 32];
    const int tid = threadIdx.x;
    const int w = tid >> 6, l = tid & 63, r = l & 15, g = l >> 4;
    const int m0 = blockIdx.y * 64, n0 = blockIdx.x * 64;
    const int col = n0 + w * 16 + r;
    const int srow = tid >> 2, sgq = tid & 3;
    f32x4 acc[4];
    const f32x4 zzv = {0.f, 0.f, 0.f, 0.f};
#pragma unroll
    for (int m = 0; m < 4; m++) acc[m] = zzv;

    const long abase = (long)(m0 + srow) * K + ((sgq ^ (srow & 3)) << 3);
    auto stage = [&](int k0, int buf) {
        __builtin_amdgcn_global_load_lds(
            (const __attribute__((address_space(1))) void*)(Agh + abase + k0),
            (__attribute__((address_space(3))) void*)&Ahs[buf][tid * 8], 16, 0, 0);
        __builtin_amdgcn_global_load_lds(
            (const __attribute__((address_space(1))) void*)(Agl + abase + k0),
            (__attribute__((address_space(3))) void*)&Als[buf][tid * 8], 16, 0, 0);
    };
    stage(0, 0);
    const long bbase = (long)col * K + g * 8;
    ushort8v bhc = *(const ushort8v*)(Bth + bbase);
    ushort8v blc = *(const ushort8v*)(Btl + bbase);

    for (int k0 = 0; k0 < K; k0 += 32) {
        const int buf = (k0 >> 5) & 1;
        asm volatile("s_waitcnt vmcnt(0)" ::: "memory");
        __builtin_amdgcn_s_barrier();
        ushort8v nbh, nbl;
        if (k0 + 32 < K) {
            stage(k0 + 32, buf ^ 1);
            nbh = *(const ushort8v*)(Bth + bbase + k0 + 32);
            nbl = *(const ushort8v*)(Btl + bbase + k0 + 32);
        }
        bf16x8 bh = __builtin_bit_cast(bf16x8, bhc);
        bf16x8 bl = __builtin_bit_cast(bf16x8, blc);
#pragma unroll
        for (int m = 0; m < 4; m++) {
            const int arow = m * 16 + r;
            const int aoff = arow * 32 + ((g ^ (arow & 3)) << 3);
            bf16x8 ah = __builtin_bit_cast(bf16x8, *(const ushort8v*)(&Ahs[buf][aoff]));
            bf16x8 al = __builtin_bit_cast(bf16x8, *(const ushort8v*)(&Als[buf][aoff]));
            acc[m] = __builtin_amdgcn_mfma_f32_16x16x32_bf16(ah, bh, acc[m], 0, 0, 0);
            acc[m] = __builtin_amdgcn_mfma_f32_16x16x32_bf16(ah, bl, acc[m], 0, 0, 0);
            acc[m] = __builtin_amdgcn_mfma_f32_16x16x32_bf16(al, bh, acc[m], 0, 0, 0);
        }
        bhc = nbh;
        blc = nbl;
    }
    const float bv = bias ? bias[col] : 0.f;
#pragma unroll
    for (int m = 0; m < 4; m++) {
#pragma unroll
        for (int q = 0; q < 4; q++) {
            const int row = m0 + m * 16 + g * 4 + q;
            float v = acc[m][q] + bv;
            if (ACT == 1) v = LRELU(v);
            if (QMASK) v *= (float)qmask[bz * M + row];
            unsigned short hi = f2bf(v);
            Ch[(long)row * N + col] = hi;
            Cl[(long)row * N + col] = f2bf(v - bf2f(hi));
        }
    }
}

// ---------------------------------------------------------------------------
// transpose hi/lo: out[b][d][s] = in[b][s][d]  (512 x 256 per batch)
// ---------------------------------------------------------------------------
__global__ __launch_bounds__(256) void transpose_hl(
    const unsigned short* __restrict__ inh, const unsigned short* __restrict__ inl,
    unsigned short* __restrict__ outh, unsigned short* __restrict__ outl) {
    __shared__ unsigned short th[32][33], tl[32][33];
    const int b = blockIdx.z;
    const int s0 = blockIdx.x * 32, d0 = blockIdx.y * 32;
    const unsigned short* ih = inh + (long)b * 512 * 256;
    const unsigned short* il = inl + (long)b * 512 * 256;
    unsigned short* oh = outh + (long)b * 256 * 512;
    unsigned short* ol = outl + (long)b * 256 * 512;
    const int tx = threadIdx.x & 31, ty = threadIdx.x >> 5;
#pragma unroll
    for (int i = 0; i < 4; i++) {
        int s = s0 + ty + i * 8;
        th[ty + i * 8][tx] = ih[(long)s * 256 + d0 + tx];
        tl[ty + i * 8][tx] = il[(long)s * 256 + d0 + tx];
    }
    __syncthreads();
#pragma unroll
    for (int i = 0; i < 4; i++) {
        int d = d0 + ty + i * 8;
        oh[(long)d * 512 + s0 + tx] = th[tx][ty + i * 8];
        ol[(long)d * 512 + s0 + tx] = tl[tx][ty + i * 8];
    }
}

// row softmax over 512; reads fp32 scores, writes probs as bf16 hi/lo
__global__ __launch_bounds__(256) void softmax_kernel(
    const float* __restrict__ S, unsigned short* __restrict__ Ph,
    unsigned short* __restrict__ Pl) {
    long row = blockIdx.x;
    const float* p = S + row * 512;
    int tid = threadIdx.x;
    __shared__ float red[8];
    float v0 = p[tid], v1 = p[tid + 256];
    float mx = fmaxf(v0, v1);
#pragma unroll
    for (int off = 32; off; off >>= 1) mx = fmaxf(mx, __shfl_down(mx, off));
    if ((tid & 63) == 0) red[tid >> 6] = mx;
    __syncthreads();
    mx = fmaxf(fmaxf(red[0], red[1]), fmaxf(red[2], red[3]));
    float e0 = expf(v0 - mx), e1 = expf(v1 - mx);
    float sm = e0 + e1;
#pragma unroll
    for (int off = 32; off; off >>= 1) sm += __shfl_down(sm, off);
    if ((tid & 63) == 0) red[4 + (tid >> 6)] = sm;
    __syncthreads();
    float inv = 1.f / (red[4] + red[5] + red[6] + red[7]);
    float w0 = e0 * inv, w1 = e1 * inv;
    unsigned short h0 = f2bf(w0), h1 = f2bf(w1);
    Ph[row * 512 + tid] = h0;
    Pl[row * 512 + tid] = f2bf(w0 - bf2f(h0));
    Ph[row * 512 + tid + 256] = h1;
    Pl[row * 512 + tid + 256] = f2bf(w1 - bf2f(h1));
}

// ---------------------------------------------------------------------------
// GRU scan v7 (round-10 best-known). 8 blocks, 512 threads, thread=(c,kq).
// Emits h as bf16 hi/lo only (fp32 no longer needed downstream).
// ---------------------------------------------------------------------------
#define D4(a0, a1, hv, uv)           \
    a0 = fmaf(hv.x, uv.x, a0);       \
    a1 = fmaf(hv.y, uv.y, a1);       \
    a0 = fmaf(hv.z, uv.z, a0);       \
    a1 = fmaf(hv.w, uv.w, a1);

__global__ __launch_bounds__(512, 2) void gru_kernel(
    const float* __restrict__ xgf, const float* __restrict__ xgb,
    const float* __restrict__ Upf, const float* __restrict__ Upb,
    const float* __restrict__ brf, const float* __restrict__ brb,
    const float* __restrict__ h0f, const float* __restrict__ h0b,
    const int* __restrict__ mask, unsigned short* __restrict__ outh,
    unsigned short* __restrict__ outl) {
    int b = blockIdx.x & 3;
    int dir = blockIdx.x >> 2;
    const float* __restrict__ xg = dir ? xgb : xgf;
    const float* __restrict__ Up = dir ? Upb : Upf;
    const float* __restrict__ br = dir ? brb : brf;
    const float* __restrict__ h0 = dir ? h0b : h0f;
    const int tid = threadIdx.x;
    const int c = tid >> 2;   // column 0..127
    const int kq = tid & 3;   // k-quad

    __shared__ __align__(16) float xs[2][16 * 384];
    __shared__ __align__(16) float hsh[2][144];
    __shared__ __align__(16) unsigned int histp[16][128];
    __shared__ unsigned long long mwords[8];

    auto stage = [&](int cc, int bufi) {
#pragma unroll
        for (int i = 0; i < 3; i++) {
            int g = i * 512 + tid;
            int j = g / 96;
            int col = (g - j * 96) * 4;
            int ts = cc * 16 + j;
            int t = dir ? (511 - ts) : ts;
            const float* src = xg + ((long)(b * 512 + t)) * 384 + col;
            __builtin_amdgcn_global_load_lds(
                (const __attribute__((address_space(1))) void*)src,
                (__attribute__((address_space(3))) void*)&xs[bufi][g * 4], 16, 0, 0);
        }
    };
    stage(0, 0);

    const float* ub = Up + (tid << 2);
    f32x4 uz0 = *(const f32x4*)(ub + 0 * 2048);
    f32x4 uz1 = *(const f32x4*)(ub + 1 * 2048);
    f32x4 uz2 = *(const f32x4*)(ub + 2 * 2048);
    f32x4 uz3 = *(const f32x4*)(ub + 3 * 2048);
    f32x4 uz4 = *(const f32x4*)(ub + 4 * 2048);
    f32x4 uz5 = *(const f32x4*)(ub + 5 * 2048);
    f32x4 uz6 = *(const f32x4*)(ub + 6 * 2048);
    f32x4 uz7 = *(const f32x4*)(ub + 7 * 2048);
    f32x4 ur0 = *(const f32x4*)(ub + 8 * 2048);
    f32x4 ur1 = *(const f32x4*)(ub + 9 * 2048);
    f32x4 ur2 = *(const f32x4*)(ub + 10 * 2048);
    f32x4 ur3 = *(const f32x4*)(ub + 11 * 2048);
    f32x4 ur4 = *(const f32x4*)(ub + 12 * 2048);
    f32x4 ur5 = *(const f32x4*)(ub + 13 * 2048);
    f32x4 ur6 = *(const f32x4*)(ub + 14 * 2048);
    f32x4 ur7 = *(const f32x4*)(ub + 15 * 2048);
    f32x4 uh0 = *(const f32x4*)(ub + 16 * 2048);
    f32x4 uh1 = *(const f32x4*)(ub + 17 * 2048);
    f32x4 uh2 = *(const f32x4*)(ub + 18 * 2048);
    f32x4 uh3 = *(const f32x4*)(ub + 19 * 2048);
    f32x4 uh4 = *(const f32x4*)(ub + 20 * 2048);
    f32x4 uh5 = *(const f32x4*)(ub + 21 * 2048);
    f32x4 uh6 = *(const f32x4*)(ub + 22 * 2048);
    f32x4 uh7 = *(const f32x4*)(ub + 23 * 2048);

    float br3[3];
#pragma unroll
    for (int g = 0; g < 3; g++) br3[g] = br[g * 128 + c];

    float hreg = h0[b * 128 + c];
    if (kq == 0) hsh[0][c + (c >> 5) * 4] = hreg;
    if (tid < 64) {
#pragma unroll
        for (int w = 0; w < 8; w++) {
            int idx = w * 64 + tid;
            int t = dir ? (511 - idx) : idx;
            unsigned long long bm = __ballot(mask[b * 512 + t] != 0);
            if (tid == 0) mwords[w] = bm;
        }
    }
    asm volatile("s_waitcnt lgkmcnt(0)" ::: "memory");
    __builtin_amdgcn_s_barrier();

    int cur = 0;
    for (int cc = 0; cc < 32; cc++) {
        asm volatile("s_waitcnt vmcnt(0)" ::: "memory");
        if (cc < 31) stage(cc + 1, (cc + 1) & 1);
        __builtin_amdgcn_s_barrier();
        const float* xb = xs[cc & 1];
        unsigned mwbits = (unsigned)((mwords[cc >> 2] >> ((cc & 3) * 16)) & 0xffffull);
#pragma unroll 1
        for (int jj = 0; jj < 16; jj++) {
            if ((mwbits >> jj) & 1) {
                const float* hp = &hsh[cur][kq * 36];
                float4 h0v = *(const float4*)(hp + 0);
                float4 h1v = *(const float4*)(hp + 4);
                float4 h2v = *(const float4*)(hp + 8);
                float4 h3v = *(const float4*)(hp + 12);
                float4 h4v = *(const float4*)(hp + 16);
                float4 h5v = *(const float4*)(hp + 20);
                float4 h6v = *(const float4*)(hp + 24);
                float4 h7v = *(const float4*)(hp + 28);
                float az0 = 0.f, az1 = 0.f, ar0 = 0.f, ar1 = 0.f, ah0 = 0.f, ah1 = 0.f;
                D4(az0, az1, h0v, uz0) D4(az0, az1, h1v, uz1)
                D4(az0, az1, h2v, uz2) D4(az0, az1, h3v, uz3)
                D4(az0, az1, h4v, uz4) D4(az0, az1, h5v, uz5)
                D4(az0, az1, h6v, uz6) D4(az0, az1, h7v, uz7)
                D4(ar0, ar1, h0v, ur0) D4(ar0, ar1, h1v, ur1)
                D4(ar0, ar1, h2v, ur2) D4(ar0, ar1, h3v, ur3)
                D4(ar0, ar1, h4v, ur4) D4(ar0, ar1, h5v, ur5)
                D4(ar0, ar1, h6v, ur6) D4(ar0, ar1, h7v, ur7)
                D4(ah0, ah1, h0v, uh0) D4(ah0, ah1, h1v, uh1)
                D4(ah0, ah1, h2v, uh2) D4(ah0, ah1, h3v, uh3)
                D4(ah0, ah1, h4v, uh4) D4(ah0, ah1, h5v, uh5)
                D4(ah0, ah1, h6v, uh6) D4(ah0, ah1, h7v, uh7)
                float rgz = dpp_add_xor2(dpp_add_xor1(az0 + az1));
                float rgr = dpp_add_xor2(dpp_add_xor1(ar0 + ar1));
                float rgh = dpp_add_xor2(dpp_add_xor1(ah0 + ah1));
                if (kq == 0) {
                    float xz = xb[jj * 384 + c];
                    float xr = xb[jj * 384 + 128 + c];
                    float xh = xb[jj * 384 + 256 + c];
                    float z = sigmoid_fast(xz + rgz + br3[0]);
                    float r_ = sigmoid_fast(xr + rgr + br3[1]);
                    float hc = tanh_fast(fmaf(r_, rgh + br3[2], xh));
                    float hn = fmaf(z, hreg - hc, hc);
                    hreg = hn;
                    hsh[cur ^ 1][c + (c >> 5) * 4] = hn;
                    unsigned short hh = f2bf(hn);
                    histp[jj][c] = (unsigned)hh |
                                   ((unsigned)f2bf(hn - bf2f(hh)) << 16);
                }
                asm volatile("s_waitcnt lgkmcnt(0)" ::: "memory");
                __builtin_amdgcn_s_barrier();
                cur ^= 1;
            } else {
                if (kq == 0) {
                    unsigned short hh = f2bf(hreg);
                    histp[jj][c] = (unsigned)hh |
                                   ((unsigned)f2bf(hreg - bf2f(hh)) << 16);
                }
            }
        }
        // chunk flush: hist -> global, coalesced, overlapped with next chunk
        asm volatile("s_waitcnt lgkmcnt(0)" ::: "memory");
        __builtin_amdgcn_s_barrier();
        {
            int fj = tid >> 5, fc = (tid & 31) << 2;
            int ts2 = cc * 16 + fj;
            int tf = dir ? (511 - ts2) : ts2;
            long ob = ((long)(b * 512 + tf)) * 256 + dir * 128 + fc;
            uint4 hp4 = *(const uint4*)&histp[fj][fc];
            u32x2 ph, pl;
            ph.x = (hp4.x & 0xffffu) | (hp4.y << 16);
            ph.y = (hp4.z & 0xffffu) | (hp4.w << 16);
            pl.x = (hp4.x >> 16) | (hp4.y & 0xffff0000u);
            pl.y = (hp4.z >> 16) | (hp4.w & 0xffff0000u);
            *(u32x2*)(outh + ob) = ph;
            *(u32x2*)(outl + ob) = pl;
        }
    }
}

// final dense 256 -> 1, one wave per row; fc2 given as bf16 hi/lo
__global__ __launch_bounds__(256) void final_kernel(
    const unsigned short* __restrict__ fh, const unsigned short* __restrict__ fl,
    const float* __restrict__ w, const float* __restrict__ b,
    float* __restrict__ out) {
    int row = blockIdx.x * 4 + (threadIdx.x >> 6);
    int lane = threadIdx.x & 63;
    const unsigned short* ah = fh + (long)row * 256;
    const unsigned short* al = fl + (long)row * 256;
    float acc = 0.f;
#pragma unroll
    for (int i = 0; i < 4; i++) {
        int idx = lane + i * 64;
        float a = bf2f(ah[idx]) + bf2f(al[idx]);
        acc = fmaf(a, w[idx], acc);
    }
#pragma unroll
    for (int off = 32; off; off >>= 1) acc += __shfl_down(acc, off);
    if (lane == 0) out[row] = acc + b[0];
}

// ---------------------------------------------------------------------------
extern "C" void kernel_launch(void* const* d_in, const int* in_sizes, int n_in,
                              void* d_out, int out_size, void* d_ws,
                              size_t ws_size, hipStream_t stream) {
    const float* x = (const float*)d_in[0];
    const unsigned int* mraw = (const unsigned int*)d_in[1];
    const float* s1f = (const float*)d_in[2];
    const float* s1b = (const float*)d_in[3];
    const float* s2f = (const float*)d_in[4];
    const float* s2b = (const float*)d_in[5];
    const float* c1w = (const float*)d_in[6];
    const float* c1b = (const float*)d_in[7];
    const float* c2w = (const float*)d_in[8];
    const float* c2b = (const float*)d_in[9];
    const float* g1fW = (const float*)d_in[10];
    const float* g1fU = (const float*)d_in[11];
    const float* g1fb = (const float*)d_in[12];
    const float* g1bW = (const float*)d_in[13];
    const float* g1bU = (const float*)d_in[14];
    const float* g1bb = (const float*)d_in[15];
    const float* g2fW = (const float*)d_in[16];
    const float* g2fU = (const float*)d_in[17];
    const float* g2fb = (const float*)d_in[18];
    const float* g2bW = (const float*)d_in[19];
    const float* g2bU = (const float*)d_in[20];
    const float* g2bb = (const float*)d_in[21];
    const float* d1w = (const float*)d_in[22];
    const float* d1b = (const float*)d_in[23];
    const float* d2w = (const float*)d_in[24];
    const float* d2b = (const float*)d_in[25];
    const float* d3w = (const float*)d_in[26];
    const float* d3b = (const float*)d_in[27];
    float* out = (float*)d_out;

    float* ws = (float*)d_ws;
    size_t off = 0;
    auto take = [&](size_t n) {  // n in floats
        float* p = ws + off;
        off += (n + 63) & ~(size_t)63;
        return p;
    };
    int* mask_i = (int*)take(2048);
    unsigned short* feat_h = (unsigned short*)take(2048UL * 1664 / 2);
    unsigned short* feat_l = (unsigned short*)take(2048UL * 1664 / 2);
    float* xg1f = take(2048UL * 384);
    float* xg1b = take(2048UL * 384);
    unsigned short* gru1h = (unsigned short*)take(2048UL * 128);
    unsigned short* gru1l = (unsigned short*)take(2048UL * 128);
    float* xg2f = take(2048UL * 384);
    float* xg2b = take(2048UL * 384);
    unsigned short* gru2h = (unsigned short*)take(2048UL * 128);
    unsigned short* gru2l = (unsigned short*)take(2048UL * 128);
    unsigned short* ght = (unsigned short*)take(2048UL * 128);  // H^T hi
    unsigned short* glt = (unsigned short*)take(2048UL * 128);  // H^T lo
    float* sc = take(4UL * 512 * 512);
    unsigned short* scH = (unsigned short*)take(4UL * 512 * 256);
    unsigned short* scL = (unsigned short*)take(4UL * 512 * 256);
    unsigned short* attnH = (unsigned short*)take(2048UL * 128);
    unsigned short* attnL = (unsigned short*)take(2048UL * 128);
    unsigned short* fc1H = (unsigned short*)take(2048UL * 128);
    unsigned short* fc1L = (unsigned short*)take(2048UL * 128);
    unsigned short* fc2H = (unsigned short*)take(2048UL * 128);
    unsigned short* fc2L = (unsigned short*)take(2048UL * 128);
    unsigned short* bth = (unsigned short*)take(65536);
    unsigned short* btl = (unsigned short*)take(65536);
    unsigned short* wt1fh = (unsigned short*)take(319488);
    unsigned short* wt1fl = (unsigned short*)take(319488);
    unsigned short* wt1bh = (unsigned short*)take(319488);
    unsigned short* wt1bl = (unsigned short*)take(319488);
    unsigned short* wt2fh = (unsigned short*)take(49152);
    unsigned short* wt2fl = (unsigned short*)take(49152);
    unsigned short* wt2bh = (unsigned short*)take(49152);
    unsigned short* wt2bl = (unsigned short*)take(49152);
    unsigned short* d1th = (unsigned short*)take(32768);
    unsigned short* d1tl = (unsigned short*)take(32768);
    unsigned short* d2th = (unsigned short*)take(32768);
    unsigned short* d2tl = (unsigned short*)take(32768);
    float* up1f = take(49152);
    float* up1b = take(49152);
    float* up2f = take(49152);
    float* up2b = take(49152);

    prepack_all<<<7553, 256, 0, stream>>>(
        c2w, bth, btl, g1fW, wt1fh, wt1fl, g1bW, wt1bh, wt1bl, g2fW, wt2fh,
        wt2fl, g2bW, wt2bh, wt2bl, g1fU, up1f, g1bU, up1b, g2fU, up2f, g2bU,
        up2b, d1w, d1th, d1tl, d2w, d2th, d2tl, mraw, mask_i);
    conv_kernel<<<2048, 256, 0, stream>>>(x, c1w, c1b, bth, btl, c2b, feat_h, feat_l);

    gemm_proj<<<dim3(6, 32, 2), 256, 0, stream>>>(
        feat_h, feat_l, wt1fh, wt1fl, wt1bh, wt1bl, g1fb, g1bb, xg1f, xg1b,
        2048, 384, 1664);
    gru_kernel<<<8, 512, 0, stream>>>(xg1f, xg1b, up1f, up1b, g1fb + 384,
                                      g1bb + 384, s1f, s1b, mask_i, gru1h, gru1l);

    gemm_proj<<<dim3(6, 32, 2), 256, 0, stream>>>(
        gru1h, gru1l, wt2fh, wt2fl, wt2bh, wt2bl, g2fb, g2bb, xg2f, xg2b,
        2048, 384, 256);
    gru_kernel<<<8, 512, 0, stream>>>(xg2f, xg2b, up2f, up2b, g2fb + 384,
                                      g2bb + 384, s2f, s2b, mask_i, gru2h, gru2l);

    transpose_hl<<<dim3(16, 8, 4), 256, 0, stream>>>(gru2h, gru2l, ght, glt);
    gemm_scores<<<dim3(8, 8, 4), 256, 0, stream>>>(gru2h, gru2l, mask_i, sc);
    softmax_kernel<<<2048, 256, 0, stream>>>(sc, scH, scL);
    // ctx = P @ H  (A = probs hi/lo, B^T = H^T hi/lo), query-mask epilogue
    gemm_v3<0, 1><<<dim3(4, 8, 4), 256, 0, stream>>>(
        scH, scL, ght, glt, nullptr, mask_i, attnH, attnL,
        512L * 512, 256L * 512, 512L * 256, 512, 256, 512);
    // dense head
    gemm_v3<1, 0><<<dim3(4, 32, 1), 256, 0, stream>>>(
        attnH, attnL, d1th, d1tl, d1b, nullptr, fc1H, fc1L,
        0, 0, 0, 2048, 256, 256);
    gemm_v3<1, 0><<<dim3(4, 32, 1), 256, 0, stream>>>(
        fc1H, fc1L, d2th, d2tl, d2b, nullptr, fc2H, fc2L,
        0, 0, 0, 2048, 256, 256);
    final_kernel<<<512, 256, 0, stream>>>(fc2H, fc2L, d3w, d3b, out);
}